// Round 7
// baseline (401.862 us; speedup 1.0000x reference)
//
#include <hip/hip_runtime.h>
#include <stdint.h>
#include <stddef.h>

typedef short bf16x8 __attribute__((ext_vector_type(8)));
typedef float f32x4 __attribute__((ext_vector_type(4)));

__device__ __forceinline__ unsigned short bf16rn(float f){
  unsigned int u = __builtin_bit_cast(unsigned int, f);
  u += 0x7fffu + ((u >> 16) & 1u);
  return (unsigned short)(u >> 16);
}

// global -> LDS direct (16B per lane). dst must be wave-uniform; HW adds lane*16.
__device__ __forceinline__ void gll16(const void* gsrc, void* ldst){
  __builtin_amdgcn_global_load_lds((const __attribute__((address_space(1))) unsigned int*)gsrc,
                                   (__attribute__((address_space(3))) unsigned int*)ldst,
                                   16, 0, 0);
}

__device__ __forceinline__ void barfence(){
  asm volatile("" ::: "memory");
  __builtin_amdgcn_s_barrier();
  asm volatile("" ::: "memory");
}

// ---------------- x fp32 -> bf16 ----------------
__global__ __launch_bounds__(256) void k_cvt_x(const float* __restrict__ x,
                                               unsigned short* __restrict__ xb, long n){
  long i = ((long)blockIdx.x * blockDim.x + threadIdx.x) * 8;
  if (i >= n) return;
  const float4* p = (const float4*)(x + i);
  float4 a = p[0], b = p[1];
  union { unsigned short h[8]; uint4 u; } r;
  r.h[0]=bf16rn(a.x); r.h[1]=bf16rn(a.y); r.h[2]=bf16rn(a.z); r.h[3]=bf16rn(a.w);
  r.h[4]=bf16rn(b.x); r.h[5]=bf16rn(b.y); r.h[6]=bf16rn(b.z); r.h[7]=bf16rn(b.w);
  *(uint4*)(xb + i) = r.u;
}

// ---------------- weight [E][K][N] fp32 -> [E][N][K] bf16 (transpose+convert) ----------------
__global__ __launch_bounds__(256) void k_cvt_w(const float* __restrict__ src,
                                               unsigned short* __restrict__ dst,
                                               int K, int N){
  __shared__ float t[32][33];
  int e = blockIdx.z, k0 = blockIdx.x * 32, n0 = blockIdx.y * 32;
  const float* s = src + (size_t)e * K * N;
  unsigned short* d = dst + (size_t)e * N * K;
  int tx = threadIdx.x, ty = threadIdx.y;
  #pragma unroll
  for (int j = 0; j < 4; j++)
    t[ty + j*8][tx] = s[(size_t)(k0 + ty + j*8) * N + n0 + tx];
  __syncthreads();
  #pragma unroll
  for (int j = 0; j < 4; j++){
    int n = ty + j*8;
    d[(size_t)(n0 + n) * K + k0 + tx] = bf16rn(t[tx][n]);
  }
}

// ---------------- gating: g=relu(x@Wg1+bg1); logits=g@Wg2+bg2; softmax ----------------
__global__ __launch_bounds__(128) void k_gating(const unsigned short* __restrict__ xb,
                                                const unsigned short* __restrict__ wg1t, // [128][1024]
                                                const float* __restrict__ bg1,
                                                const float* __restrict__ wg2,           // [128][16]
                                                const float* __restrict__ bg2,
                                                float* __restrict__ gout, int chunk_base){
  __shared__ unsigned short As[32*64];
  __shared__ unsigned short Bs[128*64];
  __shared__ float gl[32][129];
  const int t = threadIdx.x, wid = t >> 6, l = t & 63;
  const int m0 = blockIdx.x * 32;
  const int jb = l & 7, rsub = l >> 3;
  f32x4 acc[2][4];
  #pragma unroll
  for (int i=0;i<2;i++)
    #pragma unroll
    for (int j=0;j<4;j++) acc[i][j] = (f32x4)0.f;

  for (int kt = 0; kt < 16; kt++){
    int k0 = kt * 64;
    #pragma unroll
    for (int i = 0; i < 2; i++){
      int idx = wid*2 + i; int row = idx*8 + rsub;
      gll16(xb + (size_t)(m0 + row)*1024 + k0 + ((jb ^ (row & 7)) << 3), As + idx*512);
    }
    #pragma unroll
    for (int i = 0; i < 8; i++){
      int idx = wid*8 + i; int row = idx*8 + rsub;
      gll16(wg1t + (size_t)row*1024 + k0 + ((jb ^ (row & 7)) << 3), Bs + idx*512);
    }
    __syncthreads();
    #pragma unroll
    for (int ks = 0; ks < 2; ks++){
      int blk = ks*4 + (l >> 4);
      bf16x8 a[2], b[4];
      #pragma unroll
      for (int fi = 0; fi < 2; fi++){
        int r = fi*16 + (l & 15);
        a[fi] = *(const bf16x8*)(As + r*64 + ((blk ^ (r & 7)) << 3));
      }
      #pragma unroll
      for (int fj = 0; fj < 4; fj++){
        int r = wid*64 + fj*16 + (l & 15);
        b[fj] = *(const bf16x8*)(Bs + r*64 + ((blk ^ (r & 7)) << 3));
      }
      #pragma unroll
      for (int fi = 0; fi < 2; fi++)
        #pragma unroll
        for (int fj = 0; fj < 4; fj++)
          acc[fi][fj] = __builtin_amdgcn_mfma_f32_16x16x32_bf16(a[fi], b[fj], acc[fi][fj], 0, 0, 0);
    }
    __syncthreads();
  }
  #pragma unroll
  for (int fi = 0; fi < 2; fi++)
    #pragma unroll
    for (int fj = 0; fj < 4; fj++){
      int c = wid*64 + fj*16 + (l & 15);
      float bv = bg1[c];
      #pragma unroll
      for (int r = 0; r < 4; r++){
        int row = fi*16 + (l >> 4)*4 + r;
        float v = acc[fi][fj][r] + bv;
        gl[row][c] = v > 0.f ? v : 0.f;
      }
    }
  __syncthreads();
  if (t < 32){
    float le[16];
    #pragma unroll
    for (int e = 0; e < 16; e++) le[e] = bg2[e];
    for (int k = 0; k < 128; k++){
      float g = gl[t][k];
      const float* w = wg2 + k*16;
      #pragma unroll
      for (int e = 0; e < 16; e++) le[e] += g * w[e];
    }
    float m = le[0];
    #pragma unroll
    for (int e = 1; e < 16; e++) m = fmaxf(m, le[e]);
    float s = 0.f;
    #pragma unroll
    for (int e = 0; e < 16; e++){ le[e] = __expf(le[e] - m); s += le[e]; }
    float inv = 1.f / s;
    float4* o = (float4*)(gout + (size_t)(chunk_base + m0 + t)*16);
    #pragma unroll
    for (int q = 0; q < 4; q++)
      o[q] = make_float4(le[4*q]*inv, le[4*q+1]*inv, le[4*q+2]*inv, le[4*q+3]*inv);
  }
}

// ---------------- fused stage1+stage2a, BM=128, 4 waves, 2 blocks/CU ----------------
// Per block: expert e, 128 rows. h = relu(x@W1[e]+b1[e]) (128x256, in LDS),
// out2 = relu(h@W2[e]+b2[e]) (128x128), outE = out2 . W3[e] + b3[e].
// Main loop: BK=32, triple-buffered (A 8K + B 16K per buf, 3 bufs = 72K).
// Stage2: h 64K at 0, W2 chunks 2x8K at 64K..80K. Dynamic LDS = 80 KiB -> 2 blocks/CU
// (two independent barrier domains per CU: one block's MFMA overlaps the other's LDS phase).
// Row swizzle (4-slot 64B rows): slot s stored at s ^ (r&3) ^ ((r>>2)&3).
// h rows (32-slot 512B): slot s stored at s ^ (row&7).
__global__ __launch_bounds__(256, 2) void k_fused(const unsigned short* __restrict__ xb,
                                                  const unsigned short* __restrict__ w1t,
                                                  const float* __restrict__ b1,
                                                  const unsigned short* __restrict__ w2t, // [E][128][256]
                                                  const float* __restrict__ b2,
                                                  const float* __restrict__ w3,
                                                  const float* __restrict__ b3,
                                                  float* __restrict__ outE,
                                                  int chunkB){
  extern __shared__ __align__(16) char smem[];
  const int t = threadIdx.x;
  const int wid = t >> 6, l = t & 63;           // 4 waves; wave owns cols wid*64..+63
  const int l15 = l & 15, l4 = l >> 4;          // frag lane decomp
  const int l2 = l & 3, lr = l >> 2;            // staging lane decomp (slot, row-in-16)

  // XCD-clustered mapping: xcd = bid&7 serves experts {2*xcd, 2*xcd+1}
  const int bid = blockIdx.x;
  const int slot = bid >> 3;
  const int e = (bid & 7)*2 + (slot & 1);
  const int mt = slot >> 1;
  const int m0 = mt * 128, n0 = e * 256;

  auto swz4 = [](int r){ return (r & 3) ^ ((r >> 2) & 3); };

  // stage K-tile kt into buf p: A[128][32] at p*24576, B[256][32] at p*24576+8192
  auto STAGE = [&](int p, int kt){
    char* ab = smem + p*24576;
    #pragma unroll
    for (int j = 0; j < 2; j++){
      int idx = wid*2 + j;
      int r = idx*16 + lr;                      // A row 0..127
      gll16(xb + (size_t)(m0 + r)*1024 + kt*32 + ((l2 ^ swz4(r)) << 3),
            ab + idx*1024);
    }
    #pragma unroll
    for (int j = 0; j < 4; j++){
      int idx = wid*4 + j;
      int r = idx*16 + lr;                      // B row (n) 0..255
      gll16(w1t + (size_t)(n0 + r)*1024 + kt*32 + ((l2 ^ swz4(r)) << 3),
            ab + 8192 + idx*1024);
    }
  };
  auto LDA = [&](int p, int fi) -> bf16x8 {
    int r = fi*16 + l15;
    return *(const bf16x8*)(smem + p*24576 + r*64 + ((l4 ^ swz4(r)) << 4));
  };
  auto LDB = [&](int p, int fj) -> bf16x8 {
    int n = wid*64 + fj*16 + l15;
    return *(const bf16x8*)(smem + p*24576 + 8192 + n*64 + ((l4 ^ swz4(n)) << 4));
  };

  f32x4 acc[8][4];
  #pragma unroll
  for (int i = 0; i < 8; i++)
    #pragma unroll
    for (int j = 0; j < 4; j++) acc[i][j] = (f32x4)0.f;

  // prologue: stage tiles 0,1 into bufs 0,1; need tile0 landed -> vmcnt(6)
  STAGE(0, 0); STAGE(1, 1);
  asm volatile("s_waitcnt vmcnt(6)" ::: "memory");
  barfence();

  for (int kt = 0; kt < 32; ++kt){
    int nx = kt + 2; if (nx > 31) nx = 31;      // clamped dead re-stage at the tail
    STAGE((kt + 2) % 3, nx);                    // writes buf read in iter kt-1 (barrier-protected)

    bf16x8 av[8], bv[4];
    #pragma unroll
    for (int fi = 0; fi < 8; ++fi) av[fi] = LDA(kt % 3, fi);
    #pragma unroll
    for (int fj = 0; fj < 4; ++fj) bv[fj] = LDB(kt % 3, fj);

    __builtin_amdgcn_s_setprio(1);
    #pragma unroll
    for (int fi = 0; fi < 8; ++fi)
      #pragma unroll
      for (int fj = 0; fj < 4; ++fj)
        acc[fi][fj] = __builtin_amdgcn_mfma_f32_16x16x32_bf16(av[fi], bv[fj], acc[fi][fj], 0, 0, 0);
    __builtin_amdgcn_s_setprio(0);

    // tile kt+1 (issued last iter) must drain before next iter reads it; kt+2's 6 stay in flight
    asm volatile("s_waitcnt vmcnt(6)" ::: "memory");
    barfence();
  }

  // ===== fused stage 2 =====
  // drain ALL in-flight gll16 (incl. dead re-stages into buf0/1/2) before LDS reuse
  __syncthreads();

  // h[128][256] bf16 at smem[0..64K), row stride 512B, slot-XOR ^(row&7)
  {
    float bv[4];
    #pragma unroll
    for (int fj = 0; fj < 4; ++fj) bv[fj] = b1[e*256 + wid*64 + fj*16 + l15];
    #pragma unroll
    for (int fi = 0; fi < 8; ++fi)
      #pragma unroll
      for (int fj = 0; fj < 4; ++fj){
        const int col = wid*64 + fj*16 + l15;
        #pragma unroll
        for (int r = 0; r < 4; ++r){
          const int row = fi*16 + l4*4 + r;
          float v = acc[fi][fj][r] + bv[fj];
          v = v > 0.f ? v : 0.f;
          *(unsigned short*)(smem + row*512 + (((col >> 3) ^ (row & 7)) << 4) + ((col & 7) << 1)) = bf16rn(v);
        }
      }
  }

  // W2 chunks: [128 n][32 k] = 8KB, double-buffered at 64K/72K; 8 chunks
  const unsigned short* w2e = w2t + (size_t)e*(128*256);
  auto STAGE_W2 = [&](int c, int q){
    char* dbase = smem + 65536 + q*8192;
    #pragma unroll
    for (int j = 0; j < 2; j++){
      int idx = wid*2 + j;
      int r = idx*16 + lr;                      // n row 0..127
      gll16(w2e + (size_t)r*256 + c*32 + ((l2 ^ swz4(r)) << 3), dbase + idx*1024);
    }
  };
  STAGE_W2(0, 0);
  __syncthreads();   // h writes visible + chunk0 landed

  f32x4 acc2[8][2];
  #pragma unroll
  for (int i = 0; i < 8; i++)
    #pragma unroll
    for (int j = 0; j < 2; j++) acc2[i][j] = (f32x4)0.f;

  float w3v[2], b2v[2];
  #pragma unroll
  for (int fj = 0; fj < 2; ++fj){
    int n = wid*32 + fj*16 + l15;
    w3v[fj] = w3[e*128 + n];
    b2v[fj] = b2[e*128 + n];
  }

  #pragma unroll
  for (int c = 0; c < 8; ++c){
    if (c < 7) STAGE_W2(c+1, (c+1)&1);
    bf16x8 ah[8], bw[2];
    #pragma unroll
    for (int fi = 0; fi < 8; ++fi){
      int row = fi*16 + l15;
      int sl = (c*4 + l4) ^ (row & 7);
      ah[fi] = *(const bf16x8*)(smem + row*512 + (sl << 4));
    }
    #pragma unroll
    for (int fj = 0; fj < 2; ++fj){
      int n = wid*32 + fj*16 + l15;
      bw[fj] = *(const bf16x8*)(smem + 65536 + (c&1)*8192 + n*64 + ((l4 ^ swz4(n)) << 4));
    }
    __builtin_amdgcn_s_setprio(1);
    #pragma unroll
    for (int fi = 0; fi < 8; ++fi)
      #pragma unroll
      for (int fj = 0; fj < 2; ++fj)
        acc2[fi][fj] = __builtin_amdgcn_mfma_f32_16x16x32_bf16(ah[fi], bw[fj], acc2[fi][fj], 0, 0, 0);
    __builtin_amdgcn_s_setprio(0);
    __syncthreads();   // next chunk landed; buffer reads done before overwrite
  }

  // relu(+b2) . w3, 16-lane reduce, 4-wave cross reduce, write outE
  float* red = (float*)(smem + 65536);
  #pragma unroll
  for (int fi = 0; fi < 8; ++fi)
    #pragma unroll
    for (int r = 0; r < 4; ++r){
      float s = 0.f;
      #pragma unroll
      for (int fj = 0; fj < 2; ++fj){
        float v = acc2[fi][fj][r] + b2v[fj];
        v = v > 0.f ? v : 0.f;
        s += v * w3v[fj];
      }
      s += __shfl_xor(s, 1); s += __shfl_xor(s, 2);
      s += __shfl_xor(s, 4); s += __shfl_xor(s, 8);
      if (l15 == 0){
        int row = fi*16 + l4*4 + r;
        red[row*4 + wid] = s;
      }
    }
  __syncthreads();
  if (t < 128)
    outE[(size_t)e*chunkB + m0 + t] = red[t*4+0] + red[t*4+1] + red[t*4+2] + red[t*4+3] + b3[e];
}

// ---------------- stage2b: final[b] = sum_e g[b,e]*outE[e][b] ----------------
__global__ __launch_bounds__(256) void k_stage2b(const float* __restrict__ outE,
                                                 float* __restrict__ dout,
                                                 int chunk_base, int chunkB, int Btot){
  int row = blockIdx.x*256 + threadIdx.x;
  int rowg = chunk_base + row;
  const float* g = dout + Btot + (size_t)rowg*16;
  float s = 0.f;
  #pragma unroll
  for (int e = 0; e < 16; e++) s += g[e] * outE[(size_t)e*chunkB + row];
  dout[rowg] = s;
}

extern "C" void kernel_launch(void* const* d_in, const int* in_sizes, int n_in,
                              void* d_out, int out_size, void* d_ws, size_t ws_size,
                              hipStream_t stream){
  const float* x   = (const float*)d_in[0];
  const float* W1  = (const float*)d_in[1];
  const float* b1  = (const float*)d_in[2];
  const float* W2  = (const float*)d_in[3];
  const float* b2  = (const float*)d_in[4];
  const float* W3  = (const float*)d_in[5];
  const float* b3  = (const float*)d_in[6];
  const float* Wg1 = (const float*)d_in[7];
  const float* bg1 = (const float*)d_in[8];
  const float* Wg2 = (const float*)d_in[9];
  const float* bg2 = (const float*)d_in[10];
  float* out = (float*)d_out;

  const int B = in_sizes[0] / 1024;   // 32768

  char* ws = (char*)d_ws;
  size_t off = 0;
  auto alloc = [&](size_t bytes){ size_t p = off; off = (off + bytes + 255) & ~(size_t)255; return p; };
  size_t o_w1t  = alloc((size_t)16*256*1024*2);
  size_t o_w2t  = alloc((size_t)16*128*256*2);
  size_t o_wg1t = alloc((size_t)128*1024*2);
  size_t fixed = off;

  // deterministic chunk selection from ws_size (constant across calls)
  // per-row: xb 2048 B + outE 16*4 B = 2112 B
  const int cands[6] = {1, 2, 4, 8, 16, 32};
  int nc = 32;
  for (int i = 0; i < 6; i++){
    size_t cB = (size_t)B / cands[i];
    if (fixed + cB*2112 + 4096 <= ws_size){ nc = cands[i]; break; }
  }
  int chunkB = B / nc;

  size_t o_xb = alloc((size_t)chunkB*1024*2);
  size_t o_oe = alloc((size_t)chunkB*16*4);

  unsigned short* w1t  = (unsigned short*)(ws + o_w1t);
  unsigned short* w2t  = (unsigned short*)(ws + o_w2t);
  unsigned short* wg1t = (unsigned short*)(ws + o_wg1t);
  unsigned short* xb   = (unsigned short*)(ws + o_xb);
  float*          oE   = (float*)(ws + o_oe);

  // 80 KiB dynamic LDS -> 2 blocks/CU (idempotent, capture-safe)
  hipFuncSetAttribute(reinterpret_cast<const void*>(k_fused),
                      hipFuncAttributeMaxDynamicSharedMemorySize, 81920);

  // weight transpose+convert (once per call)
  k_cvt_w<<<dim3(32, 8, 16), dim3(32, 8), 0, stream>>>(W1, w1t, 1024, 256);
  k_cvt_w<<<dim3(8, 4, 16),  dim3(32, 8), 0, stream>>>(W2, w2t, 256, 128);
  k_cvt_w<<<dim3(32, 4, 1),  dim3(32, 8), 0, stream>>>(Wg1, wg1t, 1024, 128);

  for (int c = 0; c < nc; c++){
    int cb = c * chunkB;
    k_cvt_x<<<chunkB/2, 256, 0, stream>>>(x + (size_t)cb*1024, xb, (long)chunkB*1024);
    k_gating<<<chunkB/32, 128, 0, stream>>>(xb, wg1t, bg1, Wg2, bg2, out + B, cb);
    k_fused<<<(chunkB/128)*16, 256, 81920, stream>>>(xb, w1t, b1, w2t, b2, W3, b3, oE, chunkB);
    k_stage2b<<<chunkB/256, 256, 0, stream>>>(oE, out, cb, chunkB, B);
  }
}